// Round 3
// baseline (209.790 us; speedup 1.0000x reference)
//
#include <hip/hip_runtime.h>

#define M_ 32
#define T_ 50
#define NX_ 192
#define NY_ 192
#define NG_ 50
#define H_ 4
#define D_ 8
#define P_ (NG_*NG_)

#define NMC 16          // m-chunks
#define MPC 2           // m per chunk
#define NXH 2           // x halves
#define IXH 25          // ix per half
#define ROWS 50         // LDS row slots per stage (2 per ix)
#define RF4 (ROWS*48)   // float4 per stage = 2400
#define BT 256          // block threads
#define NPT 5           // points per thread (1250 points / 256)

// workspace layout in 4-byte units
#define WS_W    0                 // 32 floats: combined weights
#define WS_XI   32                // 50 ints:   x cell index
#define WS_XT   82                // 50 floats: x fraction
#define WS_XIN  132               // 50 floats: x inside mask
#define WS_YJ   192               // 1600 ints:   y cell index per (m,iy)
#define WS_YT   (192+1600)        // 1600 floats: y fraction
#define WS_YIN  (192+3200)        // 1600 floats: y inside mask
#define WS_PART 16384             // 16*2*50*2500 = 4,000,000 floats

__global__ void prep_kernel(const float* __restrict__ params_src,
                            const float* __restrict__ tgt_params,
                            const float* __restrict__ W_q,
                            const float* __restrict__ W_k,
                            const float* __restrict__ src_xgrid,
                            const float* __restrict__ src_ygrid,
                            float* __restrict__ wsf) {
  int* wsi = (int*)wsf;
  const int tid = threadIdx.x;
  const float ly_t = tgt_params[0];

  if (tid == 0) {
    float nt0 = (tgt_params[0] - 30.0f) / 90.0f;
    float nt1 = tgt_params[1] / 0.0029f;
    float nt2 = tgt_params[2] / 0.0018f;
    float q[H_ * D_];
    for (int o = 0; o < H_ * D_; o++)
      q[o] = nt0 * W_q[o * 3 + 0] + nt1 * W_q[o * 3 + 1] + nt2 * W_q[o * 3 + 2];

    float ns[M_][3];
    float logits[M_][H_];
    const float inv_sqrt_d = 1.0f / sqrtf(8.0f);
    for (int m = 0; m < M_; m++) {
      ns[m][0] = (params_src[m * 3 + 0] - 30.0f) / 90.0f;
      ns[m][1] = params_src[m * 3 + 1] / 0.0029f;
      ns[m][2] = params_src[m * 3 + 2] / 0.0018f;
      for (int h = 0; h < H_; h++) {
        float acc = 0.0f;
        for (int d = 0; d < D_; d++) {
          int o = h * D_ + d;
          float kk = ns[m][0] * W_k[o * 3 + 0] + ns[m][1] * W_k[o * 3 + 1] +
                     ns[m][2] * W_k[o * 3 + 2];
          acc += kk * q[o];
        }
        logits[m][h] = acc * inv_sqrt_d;
      }
    }
    float attn[M_];
    for (int m = 0; m < M_; m++) attn[m] = 0.0f;
    for (int h = 0; h < H_; h++) {
      float mx = -3.0e38f;
      for (int m = 0; m < M_; m++) mx = fmaxf(mx, logits[m][h]);
      float e[M_]; float s = 0.0f;
      for (int m = 0; m < M_; m++) { e[m] = expf(logits[m][h] - mx); s += e[m]; }
      for (int m = 0; m < M_; m++) attn[m] += e[m] / s;
    }
    float sw[M_];
    float ssum = 0.0f;
    for (int m = 0; m < M_; m++) {
      attn[m] *= 0.25f;
      float d0 = (ns[m][0] - nt0) / 0.2f;
      float d1 = (ns[m][1] - nt1) / 0.2f;
      float d2v = (ns[m][2] - nt2) / 0.2f;
      float dd = d0 * d0 + d1 * d1 + d2v * d2v;
      sw[m] = expf(-dd * 0.5f);
      ssum += sw[m];
    }
    float w[M_];
    float tsum = 0.0f;
    for (int m = 0; m < M_; m++) {
      w[m] = attn[m] * (sw[m] / (ssum + 1e-8f));
      tsum += w[m];
    }
    for (int m = 0; m < M_; m++) wsf[WS_W + m] = w[m] / (tsum + 1e-8f);
  }

  // x tables (all source x-grids identical; row 0)
  for (int ix = tid; ix < NG_; ix += blockDim.x) {
    float qx = (ix == NG_ - 1) ? 100.0f : (float)((double)ix * (100.0 / 49.0));
    int lo = 0, hi = NX_;
    while (lo < hi) { int mid = (lo + hi) >> 1; if (src_xgrid[mid] <= qx) lo = mid + 1; else hi = mid; }
    int i = lo - 1; i = i < 0 ? 0 : (i > NX_ - 2 ? NX_ - 2 : i);
    float g0 = src_xgrid[i], g1 = src_xgrid[i + 1];
    wsi[WS_XI + ix] = i;
    wsf[WS_XT + ix] = (qx - g0) / (g1 - g0);
    wsf[WS_XIN + ix] = (qx >= src_xgrid[0] && qx <= src_xgrid[NX_ - 1]) ? 1.0f : 0.0f;
  }

  // y tables per (m, iy)
  for (int idx = tid; idx < M_ * NG_; idx += blockDim.x) {
    int m = idx / NG_, iy = idx % NG_;
    float scale = ly_t / params_src[m * 3 + 0];
    float qy = ((iy == NG_ - 1) ? 1.0f : (float)((double)iy * (1.0 / 49.0))) * ly_t;
    const float* gy = src_ygrid + m * NY_;
    int lo = 0, hi = NY_;
    while (lo < hi) { int mid = (lo + hi) >> 1; if (gy[mid] * scale <= qy) lo = mid + 1; else hi = mid; }
    int j = lo - 1; j = j < 0 ? 0 : (j > NY_ - 2 ? NY_ - 2 : j);
    float g0 = gy[j] * scale, g1 = gy[j + 1] * scale;
    wsi[WS_YJ + idx] = j;
    wsf[WS_YT + idx] = (qy - g0) / (g1 - g0);
    wsf[WS_YIN + idx] =
        (qy >= gy[0] * scale && qy <= gy[NY_ - 1] * scale) ? 1.0f : 0.0f;
  }
}

// Stage needed field rows into LDS (coalesced float4), bilinear from LDS,
// accumulate MPC sources in registers, write per-chunk partials (no atomics).
#define ISSUE(S)                                                               \
  {                                                                            \
    const int m__ = m0 + ((S) >> 1);                                           \
    const float* f__ = ((S) & 1) ? c2 : c1;                                    \
    const size_t base__ = ((size_t)(m__ * T_ + t)) * (NX_ * NY_);              \
    _Pragma("unroll") for (int k = 0; k < 10; k++) {                           \
      int idx = tid + k * BT;                                                  \
      if (idx < RF4) {                                                         \
        int slot = idx / 48, pos = idx - slot * 48;                            \
        r[k] = *(const float4*)(f__ + base__ + s_row[slot] * NY_ + pos * 4);   \
      }                                                                        \
    }                                                                          \
  }

__global__ __launch_bounds__(BT) void interp_kernel(
    const float* __restrict__ c1, const float* __restrict__ c2,
    const float* __restrict__ wsf, float* __restrict__ part) {
  const int* wsi = (const int*)wsf;
  const int t = blockIdx.x;
  const int mc = blockIdx.y;
  const int xh = blockIdx.z;
  const int m0 = mc * MPC;
  const int tid = threadIdx.x;

  __shared__ float s_f[ROWS * NY_];       // 38.4 KB
  __shared__ int s_row[ROWS];
  __shared__ float s_xt[IXH], s_xin[IXH];
  __shared__ int s_yj[MPC][NG_];
  __shared__ float s_yt[MPC][NG_], s_yin[MPC][NG_], s_w[MPC];

  if (tid < IXH) {
    int ixg = xh * IXH + tid;
    int xi = wsi[WS_XI + ixg];
    s_row[2 * tid] = xi;
    s_row[2 * tid + 1] = xi + 1;
    s_xt[tid] = wsf[WS_XT + ixg];
    s_xin[tid] = wsf[WS_XIN + ixg];
  }
  if (tid >= 64 && tid < 64 + MPC * NG_) {
    int u = tid - 64;
    int mm = u / NG_, iy = u % NG_;
    int gi = (m0 + mm) * NG_ + iy;
    s_yj[mm][iy] = wsi[WS_YJ + gi];
    s_yt[mm][iy] = wsf[WS_YT + gi];
    s_yin[mm][iy] = wsf[WS_YIN + gi];
  }
  if (tid >= 192 && tid < 192 + MPC) s_w[tid - 192] = wsf[WS_W + m0 + (tid - 192)];
  __syncthreads();

  int pix[NPT], piy[NPT];
#pragma unroll
  for (int k = 0; k < NPT; k++) {
    int p = tid + k * BT;
    pix[k] = (p < 1250) ? (p / NG_) : 0;
    piy[k] = (p < 1250) ? (p % NG_) : 0;
  }

  float acc[NPT][2];
#pragma unroll
  for (int k = 0; k < NPT; k++) { acc[k][0] = 0.0f; acc[k][1] = 0.0f; }

  float4 r[10];
  ISSUE(0)

#pragma unroll
  for (int s = 0; s < 4; s++) {
    __syncthreads();  // previous compute done reading s_f
#pragma unroll
    for (int k = 0; k < 10; k++) {
      int idx = tid + k * BT;
      if (idx < RF4) ((float4*)s_f)[idx] = r[k];
    }
    __syncthreads();  // stage visible
    if (s == 0) ISSUE(1)
    if (s == 1) ISSUE(2)
    if (s == 2) ISSUE(3)

    const int mm = s >> 1;
    const int fld = s & 1;
    const float wm = s_w[mm];
#pragma unroll
    for (int k = 0; k < NPT; k++) {
      int p = tid + k * BT;
      if (p >= 1250) continue;
      int ixl = pix[k], iy = piy[k];
      int j = s_yj[mm][iy];
      float ty = s_yt[mm][iy];
      float ins = s_yin[mm][iy] * s_xin[ixl];
      float tx = s_xt[ixl];
      int b = (2 * ixl) * NY_ + j;
      float a00 = s_f[b], a01 = s_f[b + 1];
      float a10 = s_f[b + NY_], a11 = s_f[b + NY_ + 1];
      float v = (a00 * (1.0f - ty) + a01 * ty) * (1.0f - tx) +
                (a10 * (1.0f - ty) + a11 * ty) * tx;
      acc[k][fld] += wm * ins * v;
    }
  }

#pragma unroll
  for (int k = 0; k < NPT; k++) {
    int p = tid + k * BT;
    if (p >= 1250) continue;
    int pg = xh * 1250 + p;
    part[((size_t)(mc * 2 + 0) * T_ + t) * P_ + pg] = acc[k][0];
    part[((size_t)(mc * 2 + 1) * T_ + t) * P_ + pg] = acc[k][1];
  }
}

__global__ __launch_bounds__(256) void reduce_kernel(
    const float* __restrict__ part, const float* __restrict__ tgt_params,
    float* __restrict__ out) {
  int g = blockIdx.x * 256 + threadIdx.x;
  if (g >= 2 * T_ * P_) return;
  int f = (g >= T_ * P_) ? 1 : 0;
  int tp = g - f * (T_ * P_);
  float s = 0.0f;
#pragma unroll
  for (int mc = 0; mc < NMC; mc++)
    s += part[(size_t)(mc * 2 + f) * (T_ * P_) + tp];
  int iy = tp % NG_;
  if (f == 0 && iy == 0) s = tgt_params[1];
  if (f == 1 && iy == NG_ - 1) s = tgt_params[2];
  out[g] = s;
}

extern "C" void kernel_launch(void* const* d_in, const int* in_sizes, int n_in,
                              void* d_out, int out_size, void* d_ws, size_t ws_size,
                              hipStream_t stream) {
  const float* params_src = (const float*)d_in[0];
  const float* tgt_params = (const float*)d_in[1];
  const float* c1 = (const float*)d_in[2];
  const float* c2 = (const float*)d_in[3];
  const float* W_q = (const float*)d_in[4];
  const float* W_k = (const float*)d_in[5];
  const float* src_xgrid = (const float*)d_in[6];
  const float* src_ygrid = (const float*)d_in[7];
  float* out = (float*)d_out;
  float* wsf = (float*)d_ws;

  prep_kernel<<<1, 256, 0, stream>>>(params_src, tgt_params, W_q, W_k,
                                     src_xgrid, src_ygrid, wsf);
  dim3 grid(T_, NMC, NXH);
  interp_kernel<<<grid, BT, 0, stream>>>(c1, c2, wsf, wsf + WS_PART);
  int total = 2 * T_ * P_;
  reduce_kernel<<<(total + 255) / 256, 256, 0, stream>>>(wsf + WS_PART,
                                                         tgt_params, out);
}

// Round 4
// 191.370 us; speedup vs baseline: 1.0962x; 1.0962x over previous
//
#include <hip/hip_runtime.h>

#define M_ 32
#define T_ 50
#define NX_ 192
#define NY_ 192
#define NG_ 50
#define H_ 4
#define D_ 8
#define P_ (NG_*NG_)

#define NMC 8           // m-chunks
#define MPC 4           // m per chunk
#define NST (MPC*2)     // stages per block = 8 (m x field)
#define NXH 2           // x halves
#define IXH 25          // ix per half
#define ROWS 50         // LDS row slots per stage (2 per ix)
#define RF4 (ROWS*48)   // float4 per stage = 2400
#define BT 256          // block threads
#define NPT 5           // points per thread (1250 points / 256)

// workspace layout in 4-byte units
#define WS_W    0                 // 32 floats: combined weights
#define WS_XI   32                // 50 ints:   x cell index
#define WS_XT   82                // 50 floats: x fraction
#define WS_XIN  132               // 50 floats: x inside mask
#define WS_YJ   192               // 1600 ints:   y cell index per (m,iy)
#define WS_YT   (192+1600)        // 1600 floats: y fraction
#define WS_YIN  (192+3200)        // 1600 floats: y inside mask

// Block 0: weights (lane-parallel) + x/y tables.
// Blocks 1..: zero d_out and pre-write boundary-condition columns.
__global__ void prep_kernel(const float* __restrict__ params_src,
                            const float* __restrict__ tgt_params,
                            const float* __restrict__ W_q,
                            const float* __restrict__ W_k,
                            const float* __restrict__ src_xgrid,
                            const float* __restrict__ src_ygrid,
                            float* __restrict__ wsf,
                            float* __restrict__ out) {
  const int tid = threadIdx.x;

  if (blockIdx.x > 0) {
    int g = (blockIdx.x - 1) * BT + tid;
    if (g < 2 * T_ * P_) {
      int f = (g >= T_ * P_) ? 1 : 0;
      int iy = (g - f * (T_ * P_)) % NG_;
      float v = 0.0f;
      if (f == 0 && iy == 0) v = tgt_params[1];
      if (f == 1 && iy == NG_ - 1) v = tgt_params[2];
      out[g] = v;
    }
    return;
  }

  int* wsi = (int*)wsf;
  const float ly_t = tgt_params[0];

  // ---- combined weights: one lane per source, shuffle reductions ----
  if (tid < M_) {
    int m = tid;
    float nt0 = (tgt_params[0] - 30.0f) / 90.0f;
    float nt1 = tgt_params[1] / 0.0029f;
    float nt2 = tgt_params[2] / 0.0018f;
    float n0 = (params_src[m * 3 + 0] - 30.0f) / 90.0f;
    float n1 = params_src[m * 3 + 1] / 0.0029f;
    float n2 = params_src[m * 3 + 2] / 0.0018f;
    const float inv_sqrt_d = 1.0f / sqrtf(8.0f);
    float attn = 0.0f;
    for (int h = 0; h < H_; h++) {
      float l = 0.0f;
      for (int d = 0; d < D_; d++) {
        int o = h * D_ + d;
        float qo = nt0 * W_q[o * 3 + 0] + nt1 * W_q[o * 3 + 1] + nt2 * W_q[o * 3 + 2];
        float ko = n0 * W_k[o * 3 + 0] + n1 * W_k[o * 3 + 1] + n2 * W_k[o * 3 + 2];
        l += ko * qo;
      }
      l *= inv_sqrt_d;
      float mx = l;
      for (int off = 16; off; off >>= 1) mx = fmaxf(mx, __shfl_xor(mx, off, 32));
      float e = expf(l - mx);
      float s = e;
      for (int off = 16; off; off >>= 1) s += __shfl_xor(s, off, 32);
      attn += e / s;
    }
    attn *= 0.25f;
    float d0 = (n0 - nt0) / 0.2f;
    float d1 = (n1 - nt1) / 0.2f;
    float d2 = (n2 - nt2) / 0.2f;
    float sw = expf(-(d0 * d0 + d1 * d1 + d2 * d2) * 0.5f);
    float ssum = sw;
    for (int off = 16; off; off >>= 1) ssum += __shfl_xor(ssum, off, 32);
    float w = attn * (sw / (ssum + 1e-8f));
    float tsum = w;
    for (int off = 16; off; off >>= 1) tsum += __shfl_xor(tsum, off, 32);
    wsf[WS_W + m] = w / (tsum + 1e-8f);
  }

  // ---- x tables (all source x-grids identical; row 0) ----
  for (int ix = tid; ix < NG_; ix += blockDim.x) {
    float qx = (ix == NG_ - 1) ? 100.0f : (float)((double)ix * (100.0 / 49.0));
    int lo = 0, hi = NX_;  // searchsorted side='right'
    while (lo < hi) { int mid = (lo + hi) >> 1; if (src_xgrid[mid] <= qx) lo = mid + 1; else hi = mid; }
    int i = lo - 1; i = i < 0 ? 0 : (i > NX_ - 2 ? NX_ - 2 : i);
    float g0 = src_xgrid[i], g1 = src_xgrid[i + 1];
    wsi[WS_XI + ix] = i;
    wsf[WS_XT + ix] = (qx - g0) / (g1 - g0);
    wsf[WS_XIN + ix] = (qx >= src_xgrid[0] && qx <= src_xgrid[NX_ - 1]) ? 1.0f : 0.0f;
  }

  // ---- y tables per (m, iy) ----
  for (int idx = tid; idx < M_ * NG_; idx += blockDim.x) {
    int m = idx / NG_, iy = idx % NG_;
    float scale = ly_t / params_src[m * 3 + 0];
    float qy = ((iy == NG_ - 1) ? 1.0f : (float)((double)iy * (1.0 / 49.0))) * ly_t;
    const float* gy = src_ygrid + m * NY_;
    int lo = 0, hi = NY_;
    while (lo < hi) { int mid = (lo + hi) >> 1; if (gy[mid] * scale <= qy) lo = mid + 1; else hi = mid; }
    int j = lo - 1; j = j < 0 ? 0 : (j > NY_ - 2 ? NY_ - 2 : j);
    float g0 = gy[j] * scale, g1 = gy[j + 1] * scale;
    wsi[WS_YJ + idx] = j;
    wsf[WS_YT + idx] = (qy - g0) / (g1 - g0);
    wsf[WS_YIN + idx] =
        (qy >= gy[0] * scale && qy <= gy[NY_ - 1] * scale) ? 1.0f : 0.0f;
  }
}

// Stage needed field rows into LDS (coalesced float4), bilinear from LDS,
// accumulate MPC sources x 2 fields in registers, one guarded atomicAdd
// per (point, field) into pre-zeroed d_out. No partials, no reduce pass.
#define ISSUE(S)                                                               \
  {                                                                            \
    const int m__ = m0 + ((S) >> 1);                                           \
    const float* f__ = ((S) & 1) ? c2 : c1;                                    \
    const size_t base__ = ((size_t)(m__ * T_ + t)) * (NX_ * NY_);              \
    _Pragma("unroll") for (int k = 0; k < 10; k++) {                           \
      int idx = tid + k * BT;                                                  \
      if (idx < RF4) {                                                         \
        int slot = idx / 48, pos = idx - slot * 48;                            \
        r[k] = *(const float4*)(f__ + base__ + (int)s_row[slot] * NY_ + pos * 4); \
      }                                                                        \
    }                                                                          \
  }

__global__ __launch_bounds__(BT) void interp_kernel(
    const float* __restrict__ c1, const float* __restrict__ c2,
    const float* __restrict__ wsf, float* __restrict__ out) {
  const int* wsi = (const int*)wsf;
  const int t = blockIdx.x;
  const int mc = blockIdx.y;
  const int xh = blockIdx.z;
  const int m0 = mc * MPC;
  const int tid = threadIdx.x;

  __shared__ float s_f[ROWS * NY_];       // 38.4 KB
  __shared__ short s_row[ROWS];
  __shared__ float s_xt[IXH], s_xin[IXH];
  __shared__ short s_yj[MPC][NG_];
  __shared__ float s_yt[MPC][NG_], s_yin[MPC][NG_], s_w[MPC];

  if (tid < IXH) {
    int ixg = xh * IXH + tid;
    int xi = wsi[WS_XI + ixg];
    s_row[2 * tid] = (short)xi;
    s_row[2 * tid + 1] = (short)(xi + 1);
    s_xt[tid] = wsf[WS_XT + ixg];
    s_xin[tid] = wsf[WS_XIN + ixg];
  }
  for (int u = tid; u < MPC * NG_; u += BT) {
    int mm = u / NG_, iy = u % NG_;
    int gi = (m0 + mm) * NG_ + iy;
    s_yj[mm][iy] = (short)wsi[WS_YJ + gi];
    s_yt[mm][iy] = wsf[WS_YT + gi];
    s_yin[mm][iy] = wsf[WS_YIN + gi];
  }
  if (tid < MPC) s_w[tid] = wsf[WS_W + m0 + tid];
  __syncthreads();

  int pix[NPT], piy[NPT];
#pragma unroll
  for (int k = 0; k < NPT; k++) {
    int p = tid + k * BT;
    pix[k] = (p < 1250) ? (p / NG_) : 0;
    piy[k] = (p < 1250) ? (p % NG_) : 0;
  }

  float acc[NPT][2];
#pragma unroll
  for (int k = 0; k < NPT; k++) { acc[k][0] = 0.0f; acc[k][1] = 0.0f; }

  float4 r[10];
  ISSUE(0)

#pragma unroll
  for (int s = 0; s < NST; s++) {
    __syncthreads();  // previous compute done reading s_f
#pragma unroll
    for (int k = 0; k < 10; k++) {
      int idx = tid + k * BT;
      if (idx < RF4) ((float4*)s_f)[idx] = r[k];
    }
    __syncthreads();  // stage visible
    if (s < NST - 1) {
      switch (s) {
        case 0: ISSUE(1) break;
        case 1: ISSUE(2) break;
        case 2: ISSUE(3) break;
        case 3: ISSUE(4) break;
        case 4: ISSUE(5) break;
        case 5: ISSUE(6) break;
        case 6: ISSUE(7) break;
      }
    }

    const int mm = s >> 1;
    const int fld = s & 1;
    const float wm = s_w[mm];
#pragma unroll
    for (int k = 0; k < NPT; k++) {
      int p = tid + k * BT;
      if (p >= 1250) continue;
      int ixl = pix[k], iy = piy[k];
      int j = (int)s_yj[mm][iy];
      float ty = s_yt[mm][iy];
      float ins = s_yin[mm][iy] * s_xin[ixl];
      float tx = s_xt[ixl];
      int b = (2 * ixl) * NY_ + j;
      float a00 = s_f[b], a01 = s_f[b + 1];
      float a10 = s_f[b + NY_], a11 = s_f[b + NY_ + 1];
      float v = (a00 * (1.0f - ty) + a01 * ty) * (1.0f - tx) +
                (a10 * (1.0f - ty) + a11 * ty) * tx;
      acc[k][fld] += wm * ins * v;
    }
  }

#pragma unroll
  for (int k = 0; k < NPT; k++) {
    int p = tid + k * BT;
    if (p >= 1250) continue;
    int pg = xh * 1250 + p;
    int iy = piy[k];
    int o1 = t * P_ + pg;
    if (iy != 0) atomicAdd(&out[o1], acc[k][0]);                 // f=0, BC col untouched
    if (iy != NG_ - 1) atomicAdd(&out[T_ * P_ + o1], acc[k][1]); // f=1, BC col untouched
  }
}

extern "C" void kernel_launch(void* const* d_in, const int* in_sizes, int n_in,
                              void* d_out, int out_size, void* d_ws, size_t ws_size,
                              hipStream_t stream) {
  const float* params_src = (const float*)d_in[0];
  const float* tgt_params = (const float*)d_in[1];
  const float* c1 = (const float*)d_in[2];
  const float* c2 = (const float*)d_in[3];
  const float* W_q = (const float*)d_in[4];
  const float* W_k = (const float*)d_in[5];
  const float* src_xgrid = (const float*)d_in[6];
  const float* src_ygrid = (const float*)d_in[7];
  float* out = (float*)d_out;
  float* wsf = (float*)d_ws;

  int zero_blocks = (2 * T_ * P_ + BT - 1) / BT;  // 977
  prep_kernel<<<1 + zero_blocks, BT, 0, stream>>>(params_src, tgt_params, W_q,
                                                  W_k, src_xgrid, src_ygrid,
                                                  wsf, out);
  dim3 grid(T_, NMC, NXH);
  interp_kernel<<<grid, BT, 0, stream>>>(c1, c2, wsf, out);
}

// Round 5
// 69.689 us; speedup vs baseline: 3.0104x; 2.7461x over previous
//
#include <hip/hip_runtime.h>

#define M_ 32
#define T_ 50
#define NX_ 192
#define NY_ 192
#define NG_ 50
#define H_ 4
#define D_ 8
#define P_ (NG_*NG_)
#define WVS 4            // waves per block
#define BT 256

#define STRIDEF ((size_t)T_ * NX_ * NY_)   // per-m float stride

// workspace layout in 4-byte units
#define WS_W    0                 // 32 floats: combined weights
#define WS_XI   32                // 50 ints:   x cell index
#define WS_XT   82                // 50 floats: x fraction
#define WS_XIN  132               // 50 floats: x inside mask
#define WS_YJ   192               // 1600 ints:   y cell index per (m,iy)
#define WS_YT   (192+1600)        // 1600 floats: y fraction
#define WS_YIN  (192+3200)        // 1600 floats: y inside mask

__global__ void prep_kernel(const float* __restrict__ params_src,
                            const float* __restrict__ tgt_params,
                            const float* __restrict__ W_q,
                            const float* __restrict__ W_k,
                            const float* __restrict__ src_xgrid,
                            const float* __restrict__ src_ygrid,
                            float* __restrict__ wsf) {
  const int tid = threadIdx.x;
  int* wsi = (int*)wsf;
  const float ly_t = tgt_params[0];

  // ---- combined weights: one lane per source, shuffle reductions ----
  if (tid < M_) {
    int m = tid;
    float nt0 = (tgt_params[0] - 30.0f) / 90.0f;
    float nt1 = tgt_params[1] / 0.0029f;
    float nt2 = tgt_params[2] / 0.0018f;
    float n0 = (params_src[m * 3 + 0] - 30.0f) / 90.0f;
    float n1 = params_src[m * 3 + 1] / 0.0029f;
    float n2 = params_src[m * 3 + 2] / 0.0018f;
    const float inv_sqrt_d = 1.0f / sqrtf(8.0f);
    float attn = 0.0f;
    for (int h = 0; h < H_; h++) {
      float l = 0.0f;
      for (int d = 0; d < D_; d++) {
        int o = h * D_ + d;
        float qo = nt0 * W_q[o * 3 + 0] + nt1 * W_q[o * 3 + 1] + nt2 * W_q[o * 3 + 2];
        float ko = n0 * W_k[o * 3 + 0] + n1 * W_k[o * 3 + 1] + n2 * W_k[o * 3 + 2];
        l += ko * qo;
      }
      l *= inv_sqrt_d;
      float mx = l;
      for (int off = 16; off; off >>= 1) mx = fmaxf(mx, __shfl_xor(mx, off, 32));
      float e = expf(l - mx);
      float s = e;
      for (int off = 16; off; off >>= 1) s += __shfl_xor(s, off, 32);
      attn += e / s;
    }
    attn *= 0.25f;
    float d0 = (n0 - nt0) / 0.2f;
    float d1 = (n1 - nt1) / 0.2f;
    float d2 = (n2 - nt2) / 0.2f;
    float sw = expf(-(d0 * d0 + d1 * d1 + d2 * d2) * 0.5f);
    float ssum = sw;
    for (int off = 16; off; off >>= 1) ssum += __shfl_xor(ssum, off, 32);
    float w = attn * (sw / (ssum + 1e-8f));
    float tsum = w;
    for (int off = 16; off; off >>= 1) tsum += __shfl_xor(tsum, off, 32);
    wsf[WS_W + m] = w / (tsum + 1e-8f);
  }

  // ---- x tables (all source x-grids identical; row 0) ----
  for (int ix = tid; ix < NG_; ix += blockDim.x) {
    float qx = (ix == NG_ - 1) ? 100.0f : (float)((double)ix * (100.0 / 49.0));
    int lo = 0, hi = NX_;  // searchsorted side='right'
    while (lo < hi) { int mid = (lo + hi) >> 1; if (src_xgrid[mid] <= qx) lo = mid + 1; else hi = mid; }
    int i = lo - 1; i = i < 0 ? 0 : (i > NX_ - 2 ? NX_ - 2 : i);
    float g0 = src_xgrid[i], g1 = src_xgrid[i + 1];
    wsi[WS_XI + ix] = i;
    wsf[WS_XT + ix] = (qx - g0) / (g1 - g0);
    wsf[WS_XIN + ix] = (qx >= src_xgrid[0] && qx <= src_xgrid[NX_ - 1]) ? 1.0f : 0.0f;
  }

  // ---- y tables per (m, iy) ----
  for (int idx = tid; idx < M_ * NG_; idx += blockDim.x) {
    int m = idx / NG_, iy = idx % NG_;
    float scale = ly_t / params_src[m * 3 + 0];
    float qy = ((iy == NG_ - 1) ? 1.0f : (float)((double)iy * (1.0 / 49.0))) * ly_t;
    const float* gy = src_ygrid + m * NY_;
    int lo = 0, hi = NY_;
    while (lo < hi) { int mid = (lo + hi) >> 1; if (gy[mid] * scale <= qy) lo = mid + 1; else hi = mid; }
    int j = lo - 1; j = j < 0 ? 0 : (j > NY_ - 2 ? NY_ - 2 : j);
    float g0 = gy[j] * scale, g1 = gy[j + 1] * scale;
    wsi[WS_YJ + idx] = j;
    wsf[WS_YT + idx] = (qy - g0) / (g1 - g0);
    wsf[WS_YIN + idx] =
        (qy >= gy[0] * scale && qy <= gy[NY_ - 1] * scale) ? 1.0f : 0.0f;
  }
}

// One wave per (t, ix). Per m: stream rows (xi, xi+1) of both fields
// (3072 B, 192 coalesced float4) into a wave-private double-buffered LDS
// slab; lanes 0..49 (=iy) bilinear-read + accumulate. No barriers in the
// loop, no atomics, disjoint output stores.
__global__ __launch_bounds__(BT) void interp_kernel(
    const float* __restrict__ c1, const float* __restrict__ c2,
    const float* __restrict__ tgt_params,
    const float* __restrict__ wsf, float* __restrict__ out) {
  const int* wsi = (const int*)wsf;
  const int tid = threadIdx.x;
  const int wid = tid >> 6, lane = tid & 63;

  __shared__ float s_rows[WVS][2][4 * NY_];   // 24.6 KB
  __shared__ int   s_yj[M_ * NG_];            // 6.4 KB
  __shared__ float s_yt[M_ * NG_];            // 6.4 KB
  __shared__ float s_yin[M_ * NG_];           // 6.4 KB
  __shared__ float s_w[M_];

  for (int u = tid; u < M_ * NG_; u += BT) {
    s_yj[u] = wsi[WS_YJ + u];
    s_yt[u] = wsf[WS_YT + u];
    s_yin[u] = wsf[WS_YIN + u];
  }
  if (tid < M_) s_w[tid] = wsf[WS_W + tid];
  __syncthreads();   // tables ready; no barriers after this

  const int w = blockIdx.x * WVS + wid;       // 0..2499
  const int t = w / NG_;
  const int ix = w - t * NG_;
  const int xi = wsi[WS_XI + ix];
  const float tx = wsf[WS_XT + ix];
  const float insx = wsf[WS_XIN + ix];
  const float wx0 = 1.0f - tx;

  // chunk c = lane + 64k, c in [0,192): r = c/48 selects
  // {c1_lo, c1_hi, c2_lo, c2_hi}, pos = c%48 is the float4 within the row.
  const float *pA0, *pA1, *pA2;
  {
    const float* P[3];
#pragma unroll
    for (int k = 0; k < 3; k++) {
      int c = lane + 64 * k;
      int r = (c >= 144) ? 3 : (c >= 96) ? 2 : (c >= 48) ? 1 : 0;
      int pos = c - r * 48;
      const float* f = (r >= 2) ? c2 : c1;
      P[k] = f + ((size_t)t * NX_ + xi + (r & 1)) * NY_ + pos * 4;
    }
    pA0 = P[0]; pA1 = P[1]; pA2 = P[2];
  }
  const float *pB0 = pA0 + STRIDEF, *pB1 = pA1 + STRIDEF, *pB2 = pA2 + STRIDEF;

  float4* dsb0 = (float4*)&s_rows[wid][0][0];
  float4* dsb1 = (float4*)&s_rows[wid][1][0];
  const float* R0 = &s_rows[wid][0][0];
  const float* R1 = &s_rows[wid][1][0];

  float4 rA0 = *(const float4*)pA0, rA1 = *(const float4*)pA1, rA2 = *(const float4*)pA2;
  float4 rB0 = *(const float4*)pB0, rB1 = *(const float4*)pB1, rB2 = *(const float4*)pB2;
  pA0 += 2 * STRIDEF; pA1 += 2 * STRIDEF; pA2 += 2 * STRIDEF;
  pB0 += 2 * STRIDEF; pB1 += 2 * STRIDEF; pB2 += 2 * STRIDEF;

  float acc1 = 0.0f, acc2 = 0.0f;
  const bool act = (lane < NG_);

#pragma unroll
  for (int m = 0; m < M_; m += 2) {
    // ---- even m: write buf0, prefetch m+2, compute from buf0 ----
    dsb0[lane] = rA0; dsb0[lane + 64] = rA1; dsb0[lane + 128] = rA2;
    if (m + 2 < M_) {
      rA0 = *(const float4*)pA0; rA1 = *(const float4*)pA1; rA2 = *(const float4*)pA2;
      pA0 += 2 * STRIDEF; pA1 += 2 * STRIDEF; pA2 += 2 * STRIDEF;
    }
    if (act) {
      int j = s_yj[m * NG_ + lane];
      float ty = s_yt[m * NG_ + lane];
      float ins = insx * s_yin[m * NG_ + lane];
      float wy0 = 1.0f - ty;
      float a00 = R0[j],           a01 = R0[j + 1];
      float a10 = R0[NY_ + j],     a11 = R0[NY_ + j + 1];
      float b00 = R0[2 * NY_ + j], b01 = R0[2 * NY_ + j + 1];
      float b10 = R0[3 * NY_ + j], b11 = R0[3 * NY_ + j + 1];
      float v1 = (a00 * wy0 + a01 * ty) * wx0 + (a10 * wy0 + a11 * ty) * tx;
      float v2 = (b00 * wy0 + b01 * ty) * wx0 + (b10 * wy0 + b11 * ty) * tx;
      float wm = s_w[m] * ins;
      acc1 += wm * v1;
      acc2 += wm * v2;
    }
    // ---- odd m: write buf1, prefetch m+3, compute from buf1 ----
    dsb1[lane] = rB0; dsb1[lane + 64] = rB1; dsb1[lane + 128] = rB2;
    if (m + 3 < M_) {
      rB0 = *(const float4*)pB0; rB1 = *(const float4*)pB1; rB2 = *(const float4*)pB2;
      pB0 += 2 * STRIDEF; pB1 += 2 * STRIDEF; pB2 += 2 * STRIDEF;
    }
    if (act) {
      int j = s_yj[(m + 1) * NG_ + lane];
      float ty = s_yt[(m + 1) * NG_ + lane];
      float ins = insx * s_yin[(m + 1) * NG_ + lane];
      float wy0 = 1.0f - ty;
      float a00 = R1[j],           a01 = R1[j + 1];
      float a10 = R1[NY_ + j],     a11 = R1[NY_ + j + 1];
      float b00 = R1[2 * NY_ + j], b01 = R1[2 * NY_ + j + 1];
      float b10 = R1[3 * NY_ + j], b11 = R1[3 * NY_ + j + 1];
      float v1 = (a00 * wy0 + a01 * ty) * wx0 + (a10 * wy0 + a11 * ty) * tx;
      float v2 = (b00 * wy0 + b01 * ty) * wx0 + (b10 * wy0 + b11 * ty) * tx;
      float wm = s_w[m + 1] * ins;
      acc1 += wm * v1;
      acc2 += wm * v2;
    }
  }

  if (act) {
    int o = t * P_ + ix * NG_ + lane;
    out[o] = (lane == 0) ? tgt_params[1] : acc1;
    out[T_ * P_ + o] = (lane == NG_ - 1) ? tgt_params[2] : acc2;
  }
}

extern "C" void kernel_launch(void* const* d_in, const int* in_sizes, int n_in,
                              void* d_out, int out_size, void* d_ws, size_t ws_size,
                              hipStream_t stream) {
  const float* params_src = (const float*)d_in[0];
  const float* tgt_params = (const float*)d_in[1];
  const float* c1 = (const float*)d_in[2];
  const float* c2 = (const float*)d_in[3];
  const float* W_q = (const float*)d_in[4];
  const float* W_k = (const float*)d_in[5];
  const float* src_xgrid = (const float*)d_in[6];
  const float* src_ygrid = (const float*)d_in[7];
  float* out = (float*)d_out;
  float* wsf = (float*)d_ws;

  prep_kernel<<<1, BT, 0, stream>>>(params_src, tgt_params, W_q, W_k,
                                    src_xgrid, src_ygrid, wsf);
  int nblocks = (T_ * NG_ + WVS - 1) / WVS;   // 2500 waves / 4 = 625
  interp_kernel<<<nblocks, BT, 0, stream>>>(c1, c2, tgt_params, wsf, out);
}

// Round 6
// 52.764 us; speedup vs baseline: 3.9760x; 1.3208x over previous
//
#include <hip/hip_runtime.h>

#define M_ 32
#define T_ 50
#define NX_ 192
#define NY_ 192
#define NG_ 50
#define H_ 4
#define D_ 8
#define P_ (NG_*NG_)
#define WVS 4            // waves per block
#define BT 256

#define STRIDEF ((size_t)T_ * NX_ * NY_)   // per-m float stride

// workspace layout in 4-byte units
#define WS_W    0                 // 32 floats: combined weights
#define WS_XI   32                // 50 ints:   x cell index
#define WS_XT   82                // 50 floats: x fraction
#define WS_XIN  132               // 50 floats: x inside mask
#define WS_YJ   192               // 1600 ints:   y cell index per (m,iy)
#define WS_YT   (192+1600)        // 1600 floats: y fraction
#define WS_YIN  (192+3200)        // 1600 floats: y inside mask

// Parallel prep: block 0 = weights + x tables; blocks 1..8 = 200 y-table
// entries each (latency-bound binary searches now spread over 9 CUs).
__global__ void prep_kernel(const float* __restrict__ params_src,
                            const float* __restrict__ tgt_params,
                            const float* __restrict__ W_q,
                            const float* __restrict__ W_k,
                            const float* __restrict__ src_xgrid,
                            const float* __restrict__ src_ygrid,
                            float* __restrict__ wsf) {
  const int tid = threadIdx.x;
  int* wsi = (int*)wsf;
  const float ly_t = tgt_params[0];

  if (blockIdx.x > 0) {
    // ---- y tables per (m, iy): 200 entries per block ----
    int idx = (blockIdx.x - 1) * 200 + tid;
    if (tid < 200 && idx < M_ * NG_) {
      int m = idx / NG_, iy = idx % NG_;
      float scale = ly_t / params_src[m * 3 + 0];
      float qy = ((iy == NG_ - 1) ? 1.0f : (float)((double)iy * (1.0 / 49.0))) * ly_t;
      const float* gy = src_ygrid + m * NY_;
      int lo = 0, hi = NY_;
      while (lo < hi) { int mid = (lo + hi) >> 1; if (gy[mid] * scale <= qy) lo = mid + 1; else hi = mid; }
      int j = lo - 1; j = j < 0 ? 0 : (j > NY_ - 2 ? NY_ - 2 : j);
      float g0 = gy[j] * scale, g1 = gy[j + 1] * scale;
      wsi[WS_YJ + idx] = j;
      wsf[WS_YT + idx] = (qy - g0) / (g1 - g0);
      wsf[WS_YIN + idx] =
          (qy >= gy[0] * scale && qy <= gy[NY_ - 1] * scale) ? 1.0f : 0.0f;
    }
    return;
  }

  // ---- combined weights: one lane per source, shuffle reductions ----
  if (tid < M_) {
    int m = tid;
    float nt0 = (tgt_params[0] - 30.0f) / 90.0f;
    float nt1 = tgt_params[1] / 0.0029f;
    float nt2 = tgt_params[2] / 0.0018f;
    float n0 = (params_src[m * 3 + 0] - 30.0f) / 90.0f;
    float n1 = params_src[m * 3 + 1] / 0.0029f;
    float n2 = params_src[m * 3 + 2] / 0.0018f;
    const float inv_sqrt_d = 1.0f / sqrtf(8.0f);
    float attn = 0.0f;
    for (int h = 0; h < H_; h++) {
      float l = 0.0f;
      for (int d = 0; d < D_; d++) {
        int o = h * D_ + d;
        float qo = nt0 * W_q[o * 3 + 0] + nt1 * W_q[o * 3 + 1] + nt2 * W_q[o * 3 + 2];
        float ko = n0 * W_k[o * 3 + 0] + n1 * W_k[o * 3 + 1] + n2 * W_k[o * 3 + 2];
        l += ko * qo;
      }
      l *= inv_sqrt_d;
      float mx = l;
      for (int off = 16; off; off >>= 1) mx = fmaxf(mx, __shfl_xor(mx, off, 32));
      float e = expf(l - mx);
      float s = e;
      for (int off = 16; off; off >>= 1) s += __shfl_xor(s, off, 32);
      attn += e / s;
    }
    attn *= 0.25f;
    float d0 = (n0 - nt0) / 0.2f;
    float d1 = (n1 - nt1) / 0.2f;
    float d2 = (n2 - nt2) / 0.2f;
    float sw = expf(-(d0 * d0 + d1 * d1 + d2 * d2) * 0.5f);
    float ssum = sw;
    for (int off = 16; off; off >>= 1) ssum += __shfl_xor(ssum, off, 32);
    float w = attn * (sw / (ssum + 1e-8f));
    float tsum = w;
    for (int off = 16; off; off >>= 1) tsum += __shfl_xor(tsum, off, 32);
    wsf[WS_W + m] = w / (tsum + 1e-8f);
  }

  // ---- x tables (all source x-grids identical; row 0) ----
  for (int ix = tid; ix < NG_; ix += blockDim.x) {
    float qx = (ix == NG_ - 1) ? 100.0f : (float)((double)ix * (100.0 / 49.0));
    int lo = 0, hi = NX_;  // searchsorted side='right'
    while (lo < hi) { int mid = (lo + hi) >> 1; if (src_xgrid[mid] <= qx) lo = mid + 1; else hi = mid; }
    int i = lo - 1; i = i < 0 ? 0 : (i > NX_ - 2 ? NX_ - 2 : i);
    float g0 = src_xgrid[i], g1 = src_xgrid[i + 1];
    wsi[WS_XI + ix] = i;
    wsf[WS_XT + ix] = (qx - g0) / (g1 - g0);
    wsf[WS_XIN + ix] = (qx >= src_xgrid[0] && qx <= src_xgrid[NX_ - 1]) ? 1.0f : 0.0f;
  }
}

// One wave per (t, ix). Per m: stream rows (xi, xi+1) of both fields
// (3072 B, 192 coalesced float4) into a wave-private double-buffered LDS
// slab; lanes 0..49 (=iy) bilinear-read + accumulate. No barriers in the
// loop, no atomics, disjoint output stores.
__global__ __launch_bounds__(BT) void interp_kernel(
    const float* __restrict__ c1, const float* __restrict__ c2,
    const float* __restrict__ tgt_params,
    const float* __restrict__ wsf, float* __restrict__ out) {
  const int* wsi = (const int*)wsf;
  const int tid = threadIdx.x;
  const int wid = tid >> 6, lane = tid & 63;

  __shared__ float s_rows[WVS][2][4 * NY_];   // 24.6 KB
  __shared__ int   s_yj[M_ * NG_];            // 6.4 KB
  __shared__ float s_yt[M_ * NG_];            // 6.4 KB
  __shared__ float s_yin[M_ * NG_];           // 6.4 KB
  __shared__ float s_w[M_];

  for (int u = tid; u < M_ * NG_; u += BT) {
    s_yj[u] = wsi[WS_YJ + u];
    s_yt[u] = wsf[WS_YT + u];
    s_yin[u] = wsf[WS_YIN + u];
  }
  if (tid < M_) s_w[tid] = wsf[WS_W + tid];
  __syncthreads();   // tables ready; no barriers after this

  const int w = blockIdx.x * WVS + wid;       // 0..2499
  const int t = w / NG_;
  const int ix = w - t * NG_;
  const int xi = wsi[WS_XI + ix];
  const float tx = wsf[WS_XT + ix];
  const float insx = wsf[WS_XIN + ix];
  const float wx0 = 1.0f - tx;

  // chunk c = lane + 64k, c in [0,192): r = c/48 selects
  // {c1_lo, c1_hi, c2_lo, c2_hi}, pos = c%48 is the float4 within the row.
  const float *pA0, *pA1, *pA2;
  {
    const float* P[3];
#pragma unroll
    for (int k = 0; k < 3; k++) {
      int c = lane + 64 * k;
      int r = (c >= 144) ? 3 : (c >= 96) ? 2 : (c >= 48) ? 1 : 0;
      int pos = c - r * 48;
      const float* f = (r >= 2) ? c2 : c1;
      P[k] = f + ((size_t)t * NX_ + xi + (r & 1)) * NY_ + pos * 4;
    }
    pA0 = P[0]; pA1 = P[1]; pA2 = P[2];
  }
  const float *pB0 = pA0 + STRIDEF, *pB1 = pA1 + STRIDEF, *pB2 = pA2 + STRIDEF;

  float4* dsb0 = (float4*)&s_rows[wid][0][0];
  float4* dsb1 = (float4*)&s_rows[wid][1][0];
  const float* R0 = &s_rows[wid][0][0];
  const float* R1 = &s_rows[wid][1][0];

  float4 rA0 = *(const float4*)pA0, rA1 = *(const float4*)pA1, rA2 = *(const float4*)pA2;
  float4 rB0 = *(const float4*)pB0, rB1 = *(const float4*)pB1, rB2 = *(const float4*)pB2;
  pA0 += 2 * STRIDEF; pA1 += 2 * STRIDEF; pA2 += 2 * STRIDEF;
  pB0 += 2 * STRIDEF; pB1 += 2 * STRIDEF; pB2 += 2 * STRIDEF;

  float acc1 = 0.0f, acc2 = 0.0f;
  const bool act = (lane < NG_);

#pragma unroll
  for (int m = 0; m < M_; m += 2) {
    // ---- even m: write buf0, prefetch m+2, compute from buf0 ----
    dsb0[lane] = rA0; dsb0[lane + 64] = rA1; dsb0[lane + 128] = rA2;
    if (m + 2 < M_) {
      rA0 = *(const float4*)pA0; rA1 = *(const float4*)pA1; rA2 = *(const float4*)pA2;
      pA0 += 2 * STRIDEF; pA1 += 2 * STRIDEF; pA2 += 2 * STRIDEF;
    }
    if (act) {
      int j = s_yj[m * NG_ + lane];
      float ty = s_yt[m * NG_ + lane];
      float ins = insx * s_yin[m * NG_ + lane];
      float wy0 = 1.0f - ty;
      float a00 = R0[j],           a01 = R0[j + 1];
      float a10 = R0[NY_ + j],     a11 = R0[NY_ + j + 1];
      float b00 = R0[2 * NY_ + j], b01 = R0[2 * NY_ + j + 1];
      float b10 = R0[3 * NY_ + j], b11 = R0[3 * NY_ + j + 1];
      float v1 = (a00 * wy0 + a01 * ty) * wx0 + (a10 * wy0 + a11 * ty) * tx;
      float v2 = (b00 * wy0 + b01 * ty) * wx0 + (b10 * wy0 + b11 * ty) * tx;
      float wm = s_w[m] * ins;
      acc1 += wm * v1;
      acc2 += wm * v2;
    }
    // ---- odd m: write buf1, prefetch m+3, compute from buf1 ----
    dsb1[lane] = rB0; dsb1[lane + 64] = rB1; dsb1[lane + 128] = rB2;
    if (m + 3 < M_) {
      rB0 = *(const float4*)pB0; rB1 = *(const float4*)pB1; rB2 = *(const float4*)pB2;
      pB0 += 2 * STRIDEF; pB1 += 2 * STRIDEF; pB2 += 2 * STRIDEF;
    }
    if (act) {
      int j = s_yj[(m + 1) * NG_ + lane];
      float ty = s_yt[(m + 1) * NG_ + lane];
      float ins = insx * s_yin[(m + 1) * NG_ + lane];
      float wy0 = 1.0f - ty;
      float a00 = R1[j],           a01 = R1[j + 1];
      float a10 = R1[NY_ + j],     a11 = R1[NY_ + j + 1];
      float b00 = R1[2 * NY_ + j], b01 = R1[2 * NY_ + j + 1];
      float b10 = R1[3 * NY_ + j], b11 = R1[3 * NY_ + j + 1];
      float v1 = (a00 * wy0 + a01 * ty) * wx0 + (a10 * wy0 + a11 * ty) * tx;
      float v2 = (b00 * wy0 + b01 * ty) * wx0 + (b10 * wy0 + b11 * ty) * tx;
      float wm = s_w[m + 1] * ins;
      acc1 += wm * v1;
      acc2 += wm * v2;
    }
  }

  if (act) {
    int o = t * P_ + ix * NG_ + lane;
    out[o] = (lane == 0) ? tgt_params[1] : acc1;
    out[T_ * P_ + o] = (lane == NG_ - 1) ? tgt_params[2] : acc2;
  }
}

extern "C" void kernel_launch(void* const* d_in, const int* in_sizes, int n_in,
                              void* d_out, int out_size, void* d_ws, size_t ws_size,
                              hipStream_t stream) {
  const float* params_src = (const float*)d_in[0];
  const float* tgt_params = (const float*)d_in[1];
  const float* c1 = (const float*)d_in[2];
  const float* c2 = (const float*)d_in[3];
  const float* W_q = (const float*)d_in[4];
  const float* W_k = (const float*)d_in[5];
  const float* src_xgrid = (const float*)d_in[6];
  const float* src_ygrid = (const float*)d_in[7];
  float* out = (float*)d_out;
  float* wsf = (float*)d_ws;

  prep_kernel<<<1 + 8, BT, 0, stream>>>(params_src, tgt_params, W_q, W_k,
                                        src_xgrid, src_ygrid, wsf);
  int nblocks = (T_ * NG_ + WVS - 1) / WVS;   // 2500 waves / 4 = 625
  interp_kernel<<<nblocks, BT, 0, stream>>>(c1, c2, tgt_params, wsf, out);
}

// Round 7
// 52.722 us; speedup vs baseline: 3.9791x; 1.0008x over previous
//
#include <hip/hip_runtime.h>

#define M_ 32
#define T_ 50
#define NX_ 192
#define NY_ 192
#define NG_ 50
#define H_ 4
#define D_ 8
#define P_ (NG_*NG_)
#define WVS 4            // waves per block
#define BT 256

#define STRIDEF ((size_t)T_ * NX_ * NY_)   // per-m float stride

// Single fused kernel. Each block (redundantly) builds the interpolation
// tables with analytic-guess + verify searchsorted (grids are uniform
// linspaces, so the guess is within +-1; verify loops keep semantics
// bit-exact vs jnp.searchsorted on the actual f32 grid values), then runs
// the barrier-free wave-private row streaming loop.
// One wave per (t, ix); per m stream rows (xi, xi+1) of both fields
// (3072 B, 192 coalesced float4) into a wave-private double-buffered LDS
// slab; lanes 0..49 (=iy) bilinear-read + accumulate. No atomics,
// disjoint output stores.
__global__ __launch_bounds__(BT, 4) void fused_kernel(
    const float* __restrict__ params_src, const float* __restrict__ tgt_params,
    const float* __restrict__ c1, const float* __restrict__ c2,
    const float* __restrict__ W_q, const float* __restrict__ W_k,
    const float* __restrict__ src_xgrid, const float* __restrict__ src_ygrid,
    float* __restrict__ out) {
  const int tid = threadIdx.x;
  const int wid = tid >> 6, lane = tid & 63;

  __shared__ float s_rows[WVS][2][4 * NY_];   // 24576 B
  __shared__ float s_yt[M_ * NG_];            // 6400 B
  __shared__ float s_wyin[M_ * NG_];          // 6400 B (w[m]*yin folded)
  __shared__ unsigned char s_yj[M_ * NG_];    // 1600 B
  __shared__ unsigned char s_xi[NG_];         // 50 B
  __shared__ float s_xt[NG_];                 // 200 B
  __shared__ float s_xin[NG_];                // 200 B
  __shared__ float s_w[M_];                   // 128 B

  const float ly_t = tgt_params[0];

  // ---- combined weights: one lane per source, shuffle reductions ----
  if (tid < M_) {
    int m = tid;
    float nt0 = (tgt_params[0] - 30.0f) / 90.0f;
    float nt1 = tgt_params[1] / 0.0029f;
    float nt2 = tgt_params[2] / 0.0018f;
    float n0 = (params_src[m * 3 + 0] - 30.0f) / 90.0f;
    float n1 = params_src[m * 3 + 1] / 0.0029f;
    float n2 = params_src[m * 3 + 2] / 0.0018f;
    const float inv_sqrt_d = 1.0f / sqrtf(8.0f);
    float attn = 0.0f;
    for (int h = 0; h < H_; h++) {
      float l = 0.0f;
      for (int d = 0; d < D_; d++) {
        int o = h * D_ + d;
        float qo = nt0 * W_q[o * 3 + 0] + nt1 * W_q[o * 3 + 1] + nt2 * W_q[o * 3 + 2];
        float ko = n0 * W_k[o * 3 + 0] + n1 * W_k[o * 3 + 1] + n2 * W_k[o * 3 + 2];
        l += ko * qo;
      }
      l *= inv_sqrt_d;
      float mx = l;
      for (int off = 16; off; off >>= 1) mx = fmaxf(mx, __shfl_xor(mx, off, 32));
      float e = expf(l - mx);
      float s = e;
      for (int off = 16; off; off >>= 1) s += __shfl_xor(s, off, 32);
      attn += e / s;
    }
    attn *= 0.25f;
    float d0 = (n0 - nt0) / 0.2f;
    float d1 = (n1 - nt1) / 0.2f;
    float d2 = (n2 - nt2) / 0.2f;
    float sw = expf(-(d0 * d0 + d1 * d1 + d2 * d2) * 0.5f);
    float ssum = sw;
    for (int off = 16; off; off >>= 1) ssum += __shfl_xor(ssum, off, 32);
    float w = attn * (sw / (ssum + 1e-8f));
    float tsum = w;
    for (int off = 16; off; off >>= 1) tsum += __shfl_xor(tsum, off, 32);
    s_w[m] = w / (tsum + 1e-8f);
  }

  // ---- x table: analytic guess + verify (bit-exact searchsorted) ----
  if (tid >= 32 && tid < 32 + NG_) {
    int ix = tid - 32;
    float qx = (ix == NG_ - 1) ? 100.0f : (float)((double)ix * (100.0 / 49.0));
    int g = (int)(qx * (191.0f / 100.0f));
    g = g < 0 ? 0 : (g > NX_ - 1 ? NX_ - 1 : g);
    while (g < NX_ - 1 && src_xgrid[g + 1] <= qx) g++;
    while (g > 0 && src_xgrid[g] > qx) g--;
    int i = g > NX_ - 2 ? NX_ - 2 : g;
    float g0 = src_xgrid[i], g1 = src_xgrid[i + 1];
    s_xi[ix] = (unsigned char)i;
    s_xt[ix] = (qx - g0) / (g1 - g0);
    s_xin[ix] = (qx >= src_xgrid[0] && qx <= src_xgrid[NX_ - 1]) ? 1.0f : 0.0f;
  }

  // ---- y tables per (m, iy): analytic guess + verify ----
  for (int u = tid; u < M_ * NG_; u += BT) {
    int m = u / NG_, iy = u - m * NG_;
    float scale = ly_t / params_src[m * 3 + 0];
    float qy = ((iy == NG_ - 1) ? 1.0f : (float)((double)iy * (1.0 / 49.0))) * ly_t;
    const float* gy = src_ygrid + m * NY_;
    int g = (int)(qy * (191.0f / ly_t));
    g = g < 0 ? 0 : (g > NY_ - 1 ? NY_ - 1 : g);
    while (g < NY_ - 1 && gy[g + 1] * scale <= qy) g++;
    while (g > 0 && gy[g] * scale > qy) g--;
    int j = g > NY_ - 2 ? NY_ - 2 : g;
    float S0 = gy[j] * scale, S1 = gy[j + 1] * scale;
    s_yj[u] = (unsigned char)j;
    s_yt[u] = (qy - S0) / (S1 - S0);
    s_wyin[u] =
        (qy >= gy[0] * scale && qy <= gy[NY_ - 1] * scale) ? 1.0f : 0.0f;
  }
  __syncthreads();
  for (int u = tid; u < M_ * NG_; u += BT) s_wyin[u] *= s_w[u / NG_];
  __syncthreads();   // tables ready; no barriers after this

  const int w = blockIdx.x * WVS + wid;       // 0..2499
  const int t = w / NG_;
  const int ix = w - t * NG_;
  const int xi = (int)s_xi[ix];
  const float tx = s_xt[ix];
  const float insx = s_xin[ix];
  const float wx0 = 1.0f - tx;

  // chunk c = lane + 64k, c in [0,192): r = c/48 selects
  // {c1_lo, c1_hi, c2_lo, c2_hi}, pos = c%48 is the float4 within the row.
  const float *pA0, *pA1, *pA2;
  {
    const float* P[3];
#pragma unroll
    for (int k = 0; k < 3; k++) {
      int c = lane + 64 * k;
      int r = (c >= 144) ? 3 : (c >= 96) ? 2 : (c >= 48) ? 1 : 0;
      int pos = c - r * 48;
      const float* f = (r >= 2) ? c2 : c1;
      P[k] = f + ((size_t)t * NX_ + xi + (r & 1)) * NY_ + pos * 4;
    }
    pA0 = P[0]; pA1 = P[1]; pA2 = P[2];
  }
  const float *pB0 = pA0 + STRIDEF, *pB1 = pA1 + STRIDEF, *pB2 = pA2 + STRIDEF;

  float4* dsb0 = (float4*)&s_rows[wid][0][0];
  float4* dsb1 = (float4*)&s_rows[wid][1][0];
  const float* R0 = &s_rows[wid][0][0];
  const float* R1 = &s_rows[wid][1][0];

  float4 rA0 = *(const float4*)pA0, rA1 = *(const float4*)pA1, rA2 = *(const float4*)pA2;
  float4 rB0 = *(const float4*)pB0, rB1 = *(const float4*)pB1, rB2 = *(const float4*)pB2;
  pA0 += 2 * STRIDEF; pA1 += 2 * STRIDEF; pA2 += 2 * STRIDEF;
  pB0 += 2 * STRIDEF; pB1 += 2 * STRIDEF; pB2 += 2 * STRIDEF;

  float acc1 = 0.0f, acc2 = 0.0f;
  const bool act = (lane < NG_);

#pragma unroll
  for (int m = 0; m < M_; m += 2) {
    // ---- even m: write buf0, prefetch m+2, compute from buf0 ----
    dsb0[lane] = rA0; dsb0[lane + 64] = rA1; dsb0[lane + 128] = rA2;
    if (m + 2 < M_) {
      rA0 = *(const float4*)pA0; rA1 = *(const float4*)pA1; rA2 = *(const float4*)pA2;
      pA0 += 2 * STRIDEF; pA1 += 2 * STRIDEF; pA2 += 2 * STRIDEF;
    }
    if (act) {
      int j = (int)s_yj[m * NG_ + lane];
      float ty = s_yt[m * NG_ + lane];
      float wmins = insx * s_wyin[m * NG_ + lane];
      float wy0 = 1.0f - ty;
      float a00 = R0[j],           a01 = R0[j + 1];
      float a10 = R0[NY_ + j],     a11 = R0[NY_ + j + 1];
      float b00 = R0[2 * NY_ + j], b01 = R0[2 * NY_ + j + 1];
      float b10 = R0[3 * NY_ + j], b11 = R0[3 * NY_ + j + 1];
      float v1 = (a00 * wy0 + a01 * ty) * wx0 + (a10 * wy0 + a11 * ty) * tx;
      float v2 = (b00 * wy0 + b01 * ty) * wx0 + (b10 * wy0 + b11 * ty) * tx;
      acc1 += wmins * v1;
      acc2 += wmins * v2;
    }
    // ---- odd m: write buf1, prefetch m+3, compute from buf1 ----
    dsb1[lane] = rB0; dsb1[lane + 64] = rB1; dsb1[lane + 128] = rB2;
    if (m + 3 < M_) {
      rB0 = *(const float4*)pB0; rB1 = *(const float4*)pB1; rB2 = *(const float4*)pB2;
      pB0 += 2 * STRIDEF; pB1 += 2 * STRIDEF; pB2 += 2 * STRIDEF;
    }
    if (act) {
      int j = (int)s_yj[(m + 1) * NG_ + lane];
      float ty = s_yt[(m + 1) * NG_ + lane];
      float wmins = insx * s_wyin[(m + 1) * NG_ + lane];
      float wy0 = 1.0f - ty;
      float a00 = R1[j],           a01 = R1[j + 1];
      float a10 = R1[NY_ + j],     a11 = R1[NY_ + j + 1];
      float b00 = R1[2 * NY_ + j], b01 = R1[2 * NY_ + j + 1];
      float b10 = R1[3 * NY_ + j], b11 = R1[3 * NY_ + j + 1];
      float v1 = (a00 * wy0 + a01 * ty) * wx0 + (a10 * wy0 + a11 * ty) * tx;
      float v2 = (b00 * wy0 + b01 * ty) * wx0 + (b10 * wy0 + b11 * ty) * tx;
      acc1 += wmins * v1;
      acc2 += wmins * v2;
    }
  }

  if (act) {
    int o = t * P_ + ix * NG_ + lane;
    out[o] = (lane == 0) ? tgt_params[1] : acc1;
    out[T_ * P_ + o] = (lane == NG_ - 1) ? tgt_params[2] : acc2;
  }
}

extern "C" void kernel_launch(void* const* d_in, const int* in_sizes, int n_in,
                              void* d_out, int out_size, void* d_ws, size_t ws_size,
                              hipStream_t stream) {
  const float* params_src = (const float*)d_in[0];
  const float* tgt_params = (const float*)d_in[1];
  const float* c1 = (const float*)d_in[2];
  const float* c2 = (const float*)d_in[3];
  const float* W_q = (const float*)d_in[4];
  const float* W_k = (const float*)d_in[5];
  const float* src_xgrid = (const float*)d_in[6];
  const float* src_ygrid = (const float*)d_in[7];
  float* out = (float*)d_out;

  int nblocks = (T_ * NG_ + WVS - 1) / WVS;   // 2500 waves / 4 = 625
  fused_kernel<<<nblocks, BT, 0, stream>>>(params_src, tgt_params, c1, c2,
                                           W_q, W_k, src_xgrid, src_ygrid, out);
}